// Round 1
// baseline (445.600 us; speedup 1.0000x reference)
//
#include <hip/hip_runtime.h>
#include <cmath>

// Problem constants (from reference)
constexpr int B_ = 2, NCLS = 3, A_ = 3, D_ = 96, H_ = 96, W_ = 96, K_ = 128;
constexpr int CH = NCLS * A_;          // 9 channels in cls_logit
constexpr int SPAT = D_ * H_ * W_;     // 884736
constexpr int TOTAL = B_ * CH * SPAT;  // 15925248
constexpr float EPS_ = 1e-4f;
constexpr float BETA_ = 1.0f / 9.0f;

static __device__ __forceinline__ float sigmoid_clip(float x) {
  float s = 1.0f / (1.0f + __expf(-x));
  return fminf(fmaxf(s, EPS_), 1.0f - EPS_);
}

// ---------------- Kernel 1: negative focal loss over the full volume --------
__global__ __launch_bounds__(256) void neg_loss_kernel(
    const float* __restrict__ x, const float* __restrict__ pgt,
    float* __restrict__ acc) {
  float lsum = 0.0f, csum = 0.0f;
  const int stride = gridDim.x * blockDim.x;
  for (int idx = blockIdx.x * blockDim.x + threadIdx.x; idx < TOTAL;
       idx += stride) {
    const float logit = x[idx];
    int t = idx;
    const int w = t % W_; t /= W_;
    const int h = t % H_; t /= H_;
    const int d = t % D_; t /= D_;
    const int c = t % CH;
    const int b = t / CH;
    const int a = c - (c / A_) * A_;                 // c % 3
    const int sp = idx - (b * CH + c) * SPAT;        // spatial offset
    const float pg = pgt[(b * A_ + a) * SPAT + sp];

    const float* base = x + (b * CH + c) * SPAT;
    float mp = logit;  // center is part of the window
    if (d >= 1 && d <= D_ - 2 && h >= 1 && h <= H_ - 2 && w >= 1 &&
        w <= W_ - 2) {
      // interior fast path: fully unrolled 27-tap max at fixed offsets
      const float* p = base + sp - (H_ * W_) - W_ - 1;
#pragma unroll
      for (int dd = 0; dd < 3; ++dd) {
#pragma unroll
        for (int hh = 0; hh < 3; ++hh) {
          const float* row = p + dd * (H_ * W_) + hh * W_;
          mp = fmaxf(mp, row[0]);
          mp = fmaxf(mp, row[1]);
          mp = fmaxf(mp, row[2]);
        }
      }
    } else {
      const int d0 = max(d - 1, 0), d1 = min(d + 1, D_ - 1);
      const int h0 = max(h - 1, 0), h1 = min(h + 1, H_ - 1);
      const int w0 = max(w - 1, 0), w1 = min(w + 1, W_ - 1);
      for (int dd = d0; dd <= d1; ++dd)
        for (int hh = h0; hh <= h1; ++hh) {
          const float* row = base + (dd * H_ + hh) * W_;
          for (int ww = w0; ww <= w1; ++ww) mp = fmaxf(mp, row[ww]);
        }
    }
    const float prob = sigmoid_clip(logit);
    // negmask * peak * (prob > EPS); ALPHA = 1 so weight = prob
    if (mp == logit && pg == -1.0f && prob > EPS_) {
      lsum += -__logf(1.0f - prob) * prob;
      csum += prob;
    }
  }
  // wave shuffle reduce (wave = 64) then cross-wave via LDS
#pragma unroll
  for (int off = 32; off > 0; off >>= 1) {
    lsum += __shfl_down(lsum, off);
    csum += __shfl_down(csum, off);
  }
  __shared__ float sl[4], sc[4];
  const int lane = threadIdx.x & 63, wv = threadIdx.x >> 6;
  if (lane == 0) {
    sl[wv] = lsum;
    sc[wv] = csum;
  }
  __syncthreads();
  if (threadIdx.x == 0) {
    atomicAdd(&acc[0], sl[0] + sl[1] + sl[2] + sl[3]);
    atomicAdd(&acc[1], sc[0] + sc[1] + sc[2] + sc[3]);
  }
}

// ------ Kernel 2: K-point gathered terms + final 9-element output stack -----
__global__ __launch_bounds__(256) void small_kernel(
    const float* __restrict__ x, const float* __restrict__ rp,
    const float* __restrict__ pgt, const int* __restrict__ cprob,
    const int* __restrict__ cdiff, const float* __restrict__ dgt,
    const float* __restrict__ wcls, const float* __restrict__ acc,
    float* __restrict__ out) {
  const int tid = threadIdx.x;
  // v: l_pos, c_pos, l_oth, c_oth, l_reg, c_reg
  float v[6] = {0.f, 0.f, 0.f, 0.f, 0.f, 0.f};
  if (tid < B_ * K_) {
    const int b = tid / K_, k = tid - b * K_;
    {  // positive focal + other-class suppression
      const int* cp = cprob + (b * K_ + k) * 4;
      const int ca = cp[0];
      const float m = (ca > -1) ? 1.0f : 0.0f;
      const int a = max(ca, 0), d = max(cp[1], 0), h = max(cp[2], 0),
                ww = max(cp[3], 0);
      const int sp = (d * H_ + h) * W_ + ww;
      float po[NCLS];
#pragma unroll
      for (int c = 0; c < NCLS; ++c)
        po[c] = sigmoid_clip(x[(b * CH + c * A_ + a) * SPAT + sp]);
      const float pg = pgt[(b * A_ + a) * SPAT + sp];
      int cg = (int)pg - 1;  // astype(int32) truncation, then clip
      cg = min(max(cg, 0), NCLS - 1);
      const float pt = po[cg];
      const float wp = (1.0f - pt) * wcls[cg] * m;
      v[0] = -__logf(pt) * wp;
      v[1] = wp;
      const float ptgt = (pt > 0.5f) ? 1.0f : 0.0f;
#pragma unroll
      for (int c = 0; c < NCLS; ++c) {
        if (c == cg) continue;
        const float wo = fmaxf(po[c] - (pt - 0.1f), 0.0f) *
                         ((po[c] > 0.5f) ? 1.0f : 0.0f) * ptgt * m;
        v[2] += -__logf(1.0f - po[c]) * wo;
        v[3] += wo;
      }
    }
    {  // smooth-L1 regression
      const int* cd = cdiff + (b * K_ + k) * 4;
      const float md = (cd[0] > -1) ? 1.0f : 0.0f;
      const int a = max(cd[0], 0), d = max(cd[1], 0), h = max(cd[2], 0),
                ww = max(cd[3], 0);
      const int sp = (d * H_ + h) * W_ + ww;
#pragma unroll
      for (int j = 0; j < 6; ++j) {
        const float val = rp[(b * 6 * A_ + j * A_ + a) * SPAT + sp];
        const float tgt = dgt[(b * K_ + k) * 6 + j];
        const float n = fabsf(val - tgt);
        const float s = (n < BETA_) ? (0.5f * n * n / BETA_) : (n - 0.5f * BETA_);
        v[4] += s * md;
      }
      v[5] = md;
    }
  }
  __shared__ float red[256][6];
#pragma unroll
  for (int j = 0; j < 6; ++j) red[tid][j] = v[j];
  __syncthreads();
  for (int s = 128; s > 0; s >>= 1) {
    if (tid < s) {
#pragma unroll
      for (int j = 0; j < 6; ++j) red[tid][j] += red[tid + s][j];
    }
    __syncthreads();
  }
  if (tid == 0) {
    const float l_pos = red[0][0], c_pos = red[0][1];
    const float l_oth = red[0][2], c_oth = red[0][3];
    const float l_reg = red[0][4], c_reg = red[0][5];
    const float l_neg = acc[0], c_neg = acc[1];
    out[0] = l_pos + l_neg + l_oth + l_reg;  // all lambdas = 1
    out[1] = l_pos;
    out[2] = l_neg;
    out[3] = l_oth;
    out[4] = l_reg;
    out[5] = c_pos;
    out[6] = c_neg;
    out[7] = c_oth;
    out[8] = c_reg;
  }
}

extern "C" void kernel_launch(void* const* d_in, const int* in_sizes, int n_in,
                              void* d_out, int out_size, void* d_ws,
                              size_t ws_size, hipStream_t stream) {
  const float* cls_logit = (const float*)d_in[0];
  const float* reg_pred = (const float*)d_in[1];
  const float* prob_gt = (const float*)d_in[2];
  const int* coord_prob = (const int*)d_in[3];
  const int* coord_diff = (const int*)d_in[4];
  const float* diff_gt = (const float*)d_in[5];
  const float* weight_cls = (const float*)d_in[6];
  float* out = (float*)d_out;
  float* acc = (float*)d_ws;  // [0]=l_neg, [1]=count_neg

  hipMemsetAsync(acc, 0, 2 * sizeof(float), stream);
  neg_loss_kernel<<<2048, 256, 0, stream>>>(cls_logit, prob_gt, acc);
  small_kernel<<<1, 256, 0, stream>>>(cls_logit, reg_pred, prob_gt, coord_prob,
                                      coord_diff, diff_gt, weight_cls, acc,
                                      out);
}

// Round 2
// 300.270 us; speedup vs baseline: 1.4840x; 1.4840x over previous
//
#include <hip/hip_runtime.h>
#include <cmath>

// Problem constants (from reference)
constexpr int B_ = 2, NCLS = 3, A_ = 3, D_ = 96, H_ = 96, W_ = 96, K_ = 128;
constexpr int CH = NCLS * A_;          // 9 channels in cls_logit
constexpr int HW = H_ * W_;            // 9216
constexpr int SPAT = D_ * HW;          // 884736
constexpr float EPS_ = 1e-4f;
constexpr float BETA_ = 1.0f / 9.0f;

constexpr int DCHUNK = 48;             // d-range per block (2 chunks cover D)
constexpr int NDC = D_ / DCHUNK;       // 2
constexpr int NHP = H_ / 2;            // 48 h-pairs
// grid = B * CH * NHP * NDC = 2*9*48*2 = 1728 blocks of 192 threads (3 waves)

static __device__ __forceinline__ float sigmoid_clip(float x) {
  float s = 1.0f / (1.0f + __expf(-x));
  return fminf(fmaxf(s, EPS_), 1.0f - EPS_);
}

// ---------------- Kernel 1: negative focal loss, separable sliding max ------
__global__ __launch_bounds__(192) void neg_loss_kernel(
    const float* __restrict__ x, const float* __restrict__ pgt,
    float* __restrict__ acc) {
  // block id -> (b, c, h-pair, d-chunk)
  int blk = blockIdx.x;
  const int dci = blk % NDC; blk /= NDC;
  const int hp = blk % NHP; blk /= NHP;
  const int c = blk % CH;
  const int b = blk / CH;

  const int tid = threadIdx.x;
  const int rl = tid / W_;             // row-in-pair: 0 or 1
  const int w = tid - rl * W_;         // 0..95
  const int h = hp * 2 + rl;
  const int d0 = dci * DCHUNK;

  const float* base = x + (size_t)(b * CH + c) * SPAT;
  const int a = c - (c / A_) * A_;     // c % 3
  // per-thread fixed row pointers (h-clamped); only plane offset varies
  const int hm = max(h - 1, 0), hq = min(h + 1, H_ - 1);
  const float* rowm = base + hm * W_ + w;
  const float* rowc = base + h * W_ + w;
  const float* rowp = base + hq * W_ + w;
  const float* pgrow = pgt + (size_t)(b * A_ + a) * SPAT + h * W_ + w;

  const int wm = max(w - 1, 0), wq = min(w + 1, W_ - 1);

  __shared__ float cm[2][2][W_];       // [parity][row-in-pair][w]

  float lsum = 0.0f, csum = 0.0f;

  // s(plane) = max over the 3 h-rows at that plane; cc = center value x(d,h,w)
  float s_prev, s_cur, s_next, cc, cn;
  {
    const int plm = max(d0 - 1, 0) * HW;
    float vm = rowm[plm], vc = rowc[plm], vp = rowp[plm];
    s_prev = fmaxf(fmaxf(vm, vc), vp);
    const int pl0 = d0 * HW;
    vm = rowm[pl0]; vc = rowc[pl0]; vp = rowp[pl0];
    s_cur = fmaxf(fmaxf(vm, vc), vp);
    cc = vc;
  }

  int parity = 0;
  int offc = d0 * HW;  // center-plane element offset (for pg load)
#pragma unroll 2
  for (int d = d0; d < d0 + DCHUNK; ++d) {
    const int pln = min(d + 1, D_ - 1) * HW;
    {
      const float vm = rowm[pln], vc = rowc[pln], vp = rowp[pln];
      s_next = fmaxf(fmaxf(vm, vc), vp);
      cn = vc;
    }
    const float colmax = fmaxf(fmaxf(s_prev, s_cur), s_next);
    cm[parity][rl][w] = colmax;
    __syncthreads();
    float mp = fmaxf(colmax, fmaxf(cm[parity][rl][wm], cm[parity][rl][wq]));

    // peak + negative + prob>EPS --> accumulate
    if (mp == cc) {
      const float pg = pgrow[offc];
      if (pg == -1.0f) {
        const float prob = sigmoid_clip(cc);
        if (prob > EPS_) {
          lsum += -__logf(1.0f - prob) * prob;
          csum += prob;
        }
      }
    }
    // rotate the d-window
    s_prev = s_cur; s_cur = s_next; cc = cn;
    offc += HW;
    parity ^= 1;
  }

  // wave shuffle reduce (wave = 64) then cross-wave via LDS
#pragma unroll
  for (int off = 32; off > 0; off >>= 1) {
    lsum += __shfl_down(lsum, off);
    csum += __shfl_down(csum, off);
  }
  __shared__ float sl[3], sc[3];
  const int lane = tid & 63, wv = tid >> 6;
  if (lane == 0) { sl[wv] = lsum; sc[wv] = csum; }
  __syncthreads();
  if (tid == 0) {
    atomicAdd(&acc[0], sl[0] + sl[1] + sl[2]);
    atomicAdd(&acc[1], sc[0] + sc[1] + sc[2]);
  }
}

// ------ Kernel 2: K-point gathered terms + final 9-element output stack -----
__global__ __launch_bounds__(256) void small_kernel(
    const float* __restrict__ x, const float* __restrict__ rp,
    const float* __restrict__ pgt, const int* __restrict__ cprob,
    const int* __restrict__ cdiff, const float* __restrict__ dgt,
    const float* __restrict__ wcls, const float* __restrict__ acc,
    float* __restrict__ out) {
  const int tid = threadIdx.x;
  // v: l_pos, c_pos, l_oth, c_oth, l_reg, c_reg
  float v[6] = {0.f, 0.f, 0.f, 0.f, 0.f, 0.f};
  if (tid < B_ * K_) {
    const int b = tid / K_, k = tid - b * K_;
    {  // positive focal + other-class suppression
      const int* cp = cprob + (b * K_ + k) * 4;
      const int ca = cp[0];
      const float m = (ca > -1) ? 1.0f : 0.0f;
      const int a = max(ca, 0), d = max(cp[1], 0), h = max(cp[2], 0),
                ww = max(cp[3], 0);
      const int sp = (d * H_ + h) * W_ + ww;
      float po[NCLS];
#pragma unroll
      for (int c = 0; c < NCLS; ++c)
        po[c] = sigmoid_clip(x[(size_t)(b * CH + c * A_ + a) * SPAT + sp]);
      const float pg = pgt[(size_t)(b * A_ + a) * SPAT + sp];
      int cg = (int)pg - 1;  // astype(int32) truncation, then clip
      cg = min(max(cg, 0), NCLS - 1);
      const float pt = po[cg];
      const float wp = (1.0f - pt) * wcls[cg] * m;
      v[0] = -__logf(pt) * wp;
      v[1] = wp;
      const float ptgt = (pt > 0.5f) ? 1.0f : 0.0f;
#pragma unroll
      for (int c = 0; c < NCLS; ++c) {
        if (c == cg) continue;
        const float wo = fmaxf(po[c] - (pt - 0.1f), 0.0f) *
                         ((po[c] > 0.5f) ? 1.0f : 0.0f) * ptgt * m;
        v[2] += -__logf(1.0f - po[c]) * wo;
        v[3] += wo;
      }
    }
    {  // smooth-L1 regression
      const int* cd = cdiff + (b * K_ + k) * 4;
      const float md = (cd[0] > -1) ? 1.0f : 0.0f;
      const int a = max(cd[0], 0), d = max(cd[1], 0), h = max(cd[2], 0),
                ww = max(cd[3], 0);
      const int sp = (d * H_ + h) * W_ + ww;
#pragma unroll
      for (int j = 0; j < 6; ++j) {
        const float val = rp[(size_t)(b * 6 * A_ + j * A_ + a) * SPAT + sp];
        const float tgt = dgt[(b * K_ + k) * 6 + j];
        const float n = fabsf(val - tgt);
        const float s = (n < BETA_) ? (0.5f * n * n / BETA_) : (n - 0.5f * BETA_);
        v[4] += s * md;
      }
      v[5] = md;
    }
  }
  __shared__ float red[256][6];
#pragma unroll
  for (int j = 0; j < 6; ++j) red[tid][j] = v[j];
  __syncthreads();
  for (int s = 128; s > 0; s >>= 1) {
    if (tid < s) {
#pragma unroll
      for (int j = 0; j < 6; ++j) red[tid][j] += red[tid + s][j];
    }
    __syncthreads();
  }
  if (tid == 0) {
    const float l_pos = red[0][0], c_pos = red[0][1];
    const float l_oth = red[0][2], c_oth = red[0][3];
    const float l_reg = red[0][4], c_reg = red[0][5];
    const float l_neg = acc[0], c_neg = acc[1];
    out[0] = l_pos + l_neg + l_oth + l_reg;  // all lambdas = 1
    out[1] = l_pos;
    out[2] = l_neg;
    out[3] = l_oth;
    out[4] = l_reg;
    out[5] = c_pos;
    out[6] = c_neg;
    out[7] = c_oth;
    out[8] = c_reg;
  }
}

extern "C" void kernel_launch(void* const* d_in, const int* in_sizes, int n_in,
                              void* d_out, int out_size, void* d_ws,
                              size_t ws_size, hipStream_t stream) {
  const float* cls_logit = (const float*)d_in[0];
  const float* reg_pred = (const float*)d_in[1];
  const float* prob_gt = (const float*)d_in[2];
  const int* coord_prob = (const int*)d_in[3];
  const int* coord_diff = (const int*)d_in[4];
  const float* diff_gt = (const float*)d_in[5];
  const float* weight_cls = (const float*)d_in[6];
  float* out = (float*)d_out;
  float* acc = (float*)d_ws;  // [0]=l_neg, [1]=count_neg

  hipMemsetAsync(acc, 0, 2 * sizeof(float), stream);
  const int nblk = B_ * CH * NHP * NDC;  // 1728
  neg_loss_kernel<<<nblk, 192, 0, stream>>>(cls_logit, prob_gt, acc);
  small_kernel<<<1, 256, 0, stream>>>(cls_logit, reg_pred, prob_gt, coord_prob,
                                      coord_diff, diff_gt, weight_cls, acc,
                                      out);
}

// Round 3
// 274.772 us; speedup vs baseline: 1.6217x; 1.0928x over previous
//
#include <hip/hip_runtime.h>
#include <cmath>

// Problem constants (from reference)
constexpr int B_ = 2, NCLS = 3, A_ = 3, D_ = 96, H_ = 96, W_ = 96, K_ = 128;
constexpr int CH = NCLS * A_;          // 9 channels in cls_logit
constexpr int HW = H_ * W_;            // 9216
constexpr int SPAT = D_ * HW;          // 884736
constexpr float EPS_ = 1e-4f;
constexpr float BETA_ = 1.0f / 9.0f;

// Wave-task decomposition: one wave (64 lanes = 4 h-rows x 16 w-segments,
// 6 w per lane) covers (b, c, h-group of 4, d-chunk of 12).
constexpr int WPL = 6;                 // w per lane
constexpr int DCHUNK = 12;
constexpr int NDC = D_ / DCHUNK;       // 8
constexpr int HGRP = 4;
constexpr int NHG = H_ / HGRP;         // 24
// wave-tasks = 2*9*24*8 = 3456 -> 864 blocks of 256 (4 waves each)

static __device__ __forceinline__ float sigmoid_clip(float x) {
  float s = 1.0f / (1.0f + __expf(-x));
  return fminf(fmaxf(s, EPS_), 1.0f - EPS_);
}

static __device__ __forceinline__ void load6(const float* __restrict__ p,
                                             float* f) {
  const float2 u0 = *(const float2*)(p);
  const float2 u1 = *(const float2*)(p + 2);
  const float2 u2 = *(const float2*)(p + 4);
  f[0] = u0.x; f[1] = u0.y; f[2] = u1.x;
  f[3] = u1.y; f[4] = u2.x; f[5] = u2.y;
}

// ------- Kernel 1: negative focal loss, register sliding-window max ---------
__global__ __launch_bounds__(256) void neg_loss_kernel(
    const float* __restrict__ x, const float* __restrict__ pgt,
    float* __restrict__ acc) {
  const int tid = threadIdx.x;
  const int lane = tid & 63;
  int t = blockIdx.x * 4 + (tid >> 6);   // wave-task id
  const int dci = t % NDC; t /= NDC;
  const int hg = t % NHG; t /= NHG;
  const int c = t % CH;
  const int b = t / CH;

  const int hl = lane >> 4;              // h within group: 0..3
  const int wseg = lane & 15;            // w segment: 0..15
  const int h = hg * HGRP + hl;
  const int w0 = wseg * WPL;
  const int d0 = dci * DCHUNK;
  const int a = c - (c / A_) * A_;       // c % 3

  const float* base = x + (size_t)(b * CH + c) * SPAT;
  const int hm = max(h - 1, 0), hq = min(h + 1, H_ - 1);
  const float* rowm = base + hm * W_ + w0;
  const float* rowc = base + h * W_ + w0;
  const float* rowp = base + hq * W_ + w0;
  const float* pgb = pgt + (size_t)(b * A_ + a) * SPAT + h * W_ + w0;

  float sprev[WPL], scur[WPL], ccur[WPL];
  {
    float fm[6], fc[6], fp[6];
    const int plm = max(d0 - 1, 0) * HW;
    load6(rowm + plm, fm); load6(rowc + plm, fc); load6(rowp + plm, fp);
#pragma unroll
    for (int i = 0; i < 6; ++i) sprev[i] = fmaxf(fmaxf(fm[i], fc[i]), fp[i]);
    const int pl0 = d0 * HW;
    load6(rowm + pl0, fm); load6(rowc + pl0, fc); load6(rowp + pl0, fp);
#pragma unroll
    for (int i = 0; i < 6; ++i) {
      scur[i] = fmaxf(fmaxf(fm[i], fc[i]), fp[i]);
      ccur[i] = fc[i];
    }
  }

  float lsum = 0.0f, csum = 0.0f;
#pragma unroll 4
  for (int d = d0; d < d0 + DCHUNK; ++d) {
    float fm[6], fc[6], fp[6], snext[6], cmx[6], m[6];
    const int pln = min(d + 1, D_ - 1) * HW;
    load6(rowm + pln, fm); load6(rowc + pln, fc); load6(rowp + pln, fp);
#pragma unroll
    for (int i = 0; i < 6; ++i) snext[i] = fmaxf(fmaxf(fm[i], fc[i]), fp[i]);
#pragma unroll
    for (int i = 0; i < 6; ++i)
      cmx[i] = fmaxf(fmaxf(sprev[i], scur[i]), snext[i]);
    // cross-segment halo via wave shuffles (same h-row for wseg>0 / wseg<15)
    float left = __shfl_up(cmx[5], 1);
    float right = __shfl_down(cmx[0], 1);
    if (wseg == 0) left = cmx[0];      // w==0 clamps
    if (wseg == 15) right = cmx[5];    // w==95 clamps
    m[0] = fmaxf(left, fmaxf(cmx[0], cmx[1]));
    m[1] = fmaxf(cmx[0], fmaxf(cmx[1], cmx[2]));
    m[2] = fmaxf(cmx[1], fmaxf(cmx[2], cmx[3]));
    m[3] = fmaxf(cmx[2], fmaxf(cmx[3], cmx[4]));
    m[4] = fmaxf(cmx[3], fmaxf(cmx[4], cmx[5]));
    m[5] = fmaxf(cmx[4], fmaxf(cmx[5], right));

    const float* pgp = pgb + (size_t)d * HW;
#pragma unroll
    for (int i = 0; i < 6; ++i) {
      if (m[i] == ccur[i]) {           // NMS peak (center included, ties count)
        if (pgp[i] == -1.0f) {         // negative location
          const float prob = sigmoid_clip(ccur[i]);
          if (prob > EPS_) {
            lsum += -__logf(1.0f - prob) * prob;
            csum += prob;
          }
        }
      }
    }
#pragma unroll
    for (int i = 0; i < 6; ++i) {
      sprev[i] = scur[i]; scur[i] = snext[i]; ccur[i] = fc[i];
    }
  }

  // wave shuffle reduce then cross-wave via LDS, 2 atomics per block
#pragma unroll
  for (int off = 32; off > 0; off >>= 1) {
    lsum += __shfl_down(lsum, off);
    csum += __shfl_down(csum, off);
  }
  __shared__ float sl[4], sc[4];
  const int wv = tid >> 6;
  if (lane == 0) { sl[wv] = lsum; sc[wv] = csum; }
  __syncthreads();
  if (tid == 0) {
    atomicAdd(&acc[0], sl[0] + sl[1] + sl[2] + sl[3]);
    atomicAdd(&acc[1], sc[0] + sc[1] + sc[2] + sc[3]);
  }
}

// ------ Kernel 2: K-point gathered terms + final 9-element output stack -----
__global__ __launch_bounds__(256) void small_kernel(
    const float* __restrict__ x, const float* __restrict__ rp,
    const float* __restrict__ pgt, const int* __restrict__ cprob,
    const int* __restrict__ cdiff, const float* __restrict__ dgt,
    const float* __restrict__ wcls, const float* __restrict__ acc,
    float* __restrict__ out) {
  const int tid = threadIdx.x;
  // v: l_pos, c_pos, l_oth, c_oth, l_reg, c_reg
  float v[6] = {0.f, 0.f, 0.f, 0.f, 0.f, 0.f};
  if (tid < B_ * K_) {
    const int b = tid / K_, k = tid - b * K_;
    {  // positive focal + other-class suppression
      const int* cp = cprob + (b * K_ + k) * 4;
      const int ca = cp[0];
      const float m = (ca > -1) ? 1.0f : 0.0f;
      const int a = max(ca, 0), d = max(cp[1], 0), h = max(cp[2], 0),
                ww = max(cp[3], 0);
      const int sp = (d * H_ + h) * W_ + ww;
      float po[NCLS];
#pragma unroll
      for (int c = 0; c < NCLS; ++c)
        po[c] = sigmoid_clip(x[(size_t)(b * CH + c * A_ + a) * SPAT + sp]);
      const float pg = pgt[(size_t)(b * A_ + a) * SPAT + sp];
      int cg = (int)pg - 1;  // astype(int32) truncation, then clip
      cg = min(max(cg, 0), NCLS - 1);
      const float pt = po[cg];
      const float wp = (1.0f - pt) * wcls[cg] * m;
      v[0] = -__logf(pt) * wp;
      v[1] = wp;
      const float ptgt = (pt > 0.5f) ? 1.0f : 0.0f;
#pragma unroll
      for (int c = 0; c < NCLS; ++c) {
        if (c == cg) continue;
        const float wo = fmaxf(po[c] - (pt - 0.1f), 0.0f) *
                         ((po[c] > 0.5f) ? 1.0f : 0.0f) * ptgt * m;
        v[2] += -__logf(1.0f - po[c]) * wo;
        v[3] += wo;
      }
    }
    {  // smooth-L1 regression
      const int* cd = cdiff + (b * K_ + k) * 4;
      const float md = (cd[0] > -1) ? 1.0f : 0.0f;
      const int a = max(cd[0], 0), d = max(cd[1], 0), h = max(cd[2], 0),
                ww = max(cd[3], 0);
      const int sp = (d * H_ + h) * W_ + ww;
#pragma unroll
      for (int j = 0; j < 6; ++j) {
        const float val = rp[(size_t)(b * 6 * A_ + j * A_ + a) * SPAT + sp];
        const float tgt = dgt[(b * K_ + k) * 6 + j];
        const float n = fabsf(val - tgt);
        const float s = (n < BETA_) ? (0.5f * n * n / BETA_) : (n - 0.5f * BETA_);
        v[4] += s * md;
      }
      v[5] = md;
    }
  }
  __shared__ float red[256][6];
#pragma unroll
  for (int j = 0; j < 6; ++j) red[tid][j] = v[j];
  __syncthreads();
  for (int s = 128; s > 0; s >>= 1) {
    if (tid < s) {
#pragma unroll
      for (int j = 0; j < 6; ++j) red[tid][j] += red[tid + s][j];
    }
    __syncthreads();
  }
  if (tid == 0) {
    const float l_pos = red[0][0], c_pos = red[0][1];
    const float l_oth = red[0][2], c_oth = red[0][3];
    const float l_reg = red[0][4], c_reg = red[0][5];
    const float l_neg = acc[0], c_neg = acc[1];
    out[0] = l_pos + l_neg + l_oth + l_reg;  // all lambdas = 1
    out[1] = l_pos;
    out[2] = l_neg;
    out[3] = l_oth;
    out[4] = l_reg;
    out[5] = c_pos;
    out[6] = c_neg;
    out[7] = c_oth;
    out[8] = c_reg;
  }
}

extern "C" void kernel_launch(void* const* d_in, const int* in_sizes, int n_in,
                              void* d_out, int out_size, void* d_ws,
                              size_t ws_size, hipStream_t stream) {
  const float* cls_logit = (const float*)d_in[0];
  const float* reg_pred = (const float*)d_in[1];
  const float* prob_gt = (const float*)d_in[2];
  const int* coord_prob = (const int*)d_in[3];
  const int* coord_diff = (const int*)d_in[4];
  const float* diff_gt = (const float*)d_in[5];
  const float* weight_cls = (const float*)d_in[6];
  float* out = (float*)d_out;
  float* acc = (float*)d_ws;  // [0]=l_neg, [1]=count_neg

  hipMemsetAsync(acc, 0, 2 * sizeof(float), stream);
  const int nwaves = B_ * CH * NHG * NDC;   // 3456
  const int nblk = nwaves / 4;              // 864 blocks x 4 waves
  neg_loss_kernel<<<nblk, 256, 0, stream>>>(cls_logit, prob_gt, acc);
  small_kernel<<<1, 256, 0, stream>>>(cls_logit, reg_pred, prob_gt, coord_prob,
                                      coord_diff, diff_gt, weight_cls, acc,
                                      out);
}

// Round 4
// 253.528 us; speedup vs baseline: 1.7576x; 1.0838x over previous
//
#include <hip/hip_runtime.h>
#include <cmath>

// Problem constants (from reference)
constexpr int B_ = 2, NCLS = 3, A_ = 3, D_ = 96, H_ = 96, W_ = 96, K_ = 128;
constexpr int CH = NCLS * A_;          // 9 channels in cls_logit
constexpr int HW = H_ * W_;            // 9216
constexpr int SPAT = D_ * HW;          // 884736
constexpr float EPS_ = 1e-4f;
constexpr float BETA_ = 1.0f / 9.0f;

// Wave-task decomposition: one wave (64 lanes = 4 h-rows x 16 w-segments,
// 6 w per lane) covers (b, c, h-group of 4, d-chunk of 6).
constexpr int WPL = 6;                 // w per lane
constexpr int DCHUNK = 6;
constexpr int NDC = D_ / DCHUNK;       // 16
constexpr int HGRP = 4;
constexpr int NHG = H_ / HGRP;         // 24
constexpr int NWAVES = B_ * CH * NHG * NDC;  // 6912
constexpr int NBLK = NWAVES / 4;             // 1728 blocks x 256 threads

static __device__ __forceinline__ float sigmoid_clip(float x) {
  float s = 1.0f / (1.0f + __expf(-x));
  return fminf(fmaxf(s, EPS_), 1.0f - EPS_);
}

static __device__ __forceinline__ void load6(const float* __restrict__ p,
                                             float* f) {
  const float2 u0 = *(const float2*)(p);
  const float2 u1 = *(const float2*)(p + 2);
  const float2 u2 = *(const float2*)(p + 4);
  f[0] = u0.x; f[1] = u0.y; f[2] = u1.x;
  f[3] = u1.y; f[4] = u2.x; f[5] = u2.y;
}

// ------- Kernel 1: negative focal loss, register sliding-window max ---------
// Writes per-block partial sums to ws[blk] (l_neg) and ws[NBLK+blk] (count).
__global__ __launch_bounds__(256) void neg_loss_kernel(
    const float* __restrict__ x, const float* __restrict__ pgt,
    float* __restrict__ ws) {
  const int tid = threadIdx.x;
  const int lane = tid & 63;
  int t = blockIdx.x * 4 + (tid >> 6);   // wave-task id
  const int dci = t % NDC; t /= NDC;
  const int hg = t % NHG; t /= NHG;
  const int c = t % CH;
  const int b = t / CH;

  const int hl = lane >> 4;              // h within group: 0..3
  const int wseg = lane & 15;            // w segment: 0..15
  const int h = hg * HGRP + hl;
  const int w0 = wseg * WPL;
  const int d0 = dci * DCHUNK;
  const int a = c - (c / A_) * A_;       // c % 3

  const float* base = x + (size_t)(b * CH + c) * SPAT;
  const int hm = max(h - 1, 0), hq = min(h + 1, H_ - 1);
  const float* rowm = base + hm * W_ + w0;
  const float* rowc = base + h * W_ + w0;
  const float* rowp = base + hq * W_ + w0;
  const float* pgb = pgt + (size_t)(b * A_ + a) * SPAT + h * W_ + w0;

  float sprev[WPL], scur[WPL], ccur[WPL];
  float nm[6], nc[6], np[6];             // prefetched plane d+1 (raw rows)
  {
    float fm[6], fc[6], fp[6];
    const int plm = max(d0 - 1, 0) * HW;
    load6(rowm + plm, fm); load6(rowc + plm, fc); load6(rowp + plm, fp);
    const int pl0 = d0 * HW;
    float gm[6], gc[6], gp[6];
    load6(rowm + pl0, gm); load6(rowc + pl0, gc); load6(rowp + pl0, gp);
    // prefetch plane d0+1
    const int pl1 = min(d0 + 1, D_ - 1) * HW;
    load6(rowm + pl1, nm); load6(rowc + pl1, nc); load6(rowp + pl1, np);
#pragma unroll
    for (int i = 0; i < 6; ++i) sprev[i] = fmaxf(fmaxf(fm[i], fc[i]), fp[i]);
#pragma unroll
    for (int i = 0; i < 6; ++i) {
      scur[i] = fmaxf(fmaxf(gm[i], gc[i]), gp[i]);
      ccur[i] = gc[i];
    }
  }

  float lsum = 0.0f, csum = 0.0f;
#pragma unroll
  for (int k = 0; k < DCHUNK; ++k) {
    const int d = d0 + k;
    // consume prefetched plane d+1 (loads issued a full iteration ago)
    float snext[6], cnext[6];
#pragma unroll
    for (int i = 0; i < 6; ++i) {
      snext[i] = fmaxf(fmaxf(nm[i], nc[i]), np[i]);
      cnext[i] = nc[i];
    }
    // issue prefetch for plane d+2 (consumed next iteration)
    const int pl2 = min(d + 2, D_ - 1) * HW;
    load6(rowm + pl2, nm); load6(rowc + pl2, nc); load6(rowp + pl2, np);

    float cmx[6], m[6];
#pragma unroll
    for (int i = 0; i < 6; ++i)
      cmx[i] = fmaxf(fmaxf(sprev[i], scur[i]), snext[i]);
    // cross-segment halo via wave shuffles (same h-row for wseg>0 / wseg<15)
    float left = __shfl_up(cmx[5], 1);
    float right = __shfl_down(cmx[0], 1);
    if (wseg == 0) left = cmx[0];      // w==0 clamps
    if (wseg == 15) right = cmx[5];    // w==95 clamps
    m[0] = fmaxf(left, fmaxf(cmx[0], cmx[1]));
    m[1] = fmaxf(cmx[0], fmaxf(cmx[1], cmx[2]));
    m[2] = fmaxf(cmx[1], fmaxf(cmx[2], cmx[3]));
    m[3] = fmaxf(cmx[2], fmaxf(cmx[3], cmx[4]));
    m[4] = fmaxf(cmx[3], fmaxf(cmx[4], cmx[5]));
    m[5] = fmaxf(cmx[4], fmaxf(cmx[5], right));

    const float* pgp = pgb + (size_t)d * HW;
#pragma unroll
    for (int i = 0; i < 6; ++i) {
      if (m[i] == ccur[i]) {           // NMS peak (center included, ties count)
        if (pgp[i] == -1.0f) {         // negative location
          const float prob = sigmoid_clip(ccur[i]);
          if (prob > EPS_) {
            lsum += -__logf(1.0f - prob) * prob;
            csum += prob;
          }
        }
      }
    }
#pragma unroll
    for (int i = 0; i < 6; ++i) {
      sprev[i] = scur[i]; scur[i] = snext[i]; ccur[i] = cnext[i];
    }
  }

  // wave shuffle reduce then cross-wave via LDS; per-block partial to ws
#pragma unroll
  for (int off = 32; off > 0; off >>= 1) {
    lsum += __shfl_down(lsum, off);
    csum += __shfl_down(csum, off);
  }
  __shared__ float sl[4], sc[4];
  const int wv = tid >> 6;
  if (lane == 0) { sl[wv] = lsum; sc[wv] = csum; }
  __syncthreads();
  if (tid == 0) {
    ws[blockIdx.x] = sl[0] + sl[1] + sl[2] + sl[3];
    ws[NBLK + blockIdx.x] = sc[0] + sc[1] + sc[2] + sc[3];
  }
}

// ------ Kernel 2: K-point gathered terms + partial-sum reduce + output ------
__global__ __launch_bounds__(256) void small_kernel(
    const float* __restrict__ x, const float* __restrict__ rp,
    const float* __restrict__ pgt, const int* __restrict__ cprob,
    const int* __restrict__ cdiff, const float* __restrict__ dgt,
    const float* __restrict__ wcls, const float* __restrict__ ws,
    float* __restrict__ out) {
  const int tid = threadIdx.x;
  // v: l_pos, c_pos, l_oth, c_oth, l_reg, c_reg, l_neg, c_neg
  float v[8] = {0.f, 0.f, 0.f, 0.f, 0.f, 0.f, 0.f, 0.f};
  // reduce neg-loss per-block partials (coalesced strided)
  for (int i = tid; i < NBLK; i += 256) {
    v[6] += ws[i];
    v[7] += ws[NBLK + i];
  }
  if (tid < B_ * K_) {
    const int b = tid / K_, k = tid - b * K_;
    {  // positive focal + other-class suppression
      const int* cp = cprob + (b * K_ + k) * 4;
      const int ca = cp[0];
      const float m = (ca > -1) ? 1.0f : 0.0f;
      const int a = max(ca, 0), d = max(cp[1], 0), h = max(cp[2], 0),
                ww = max(cp[3], 0);
      const int sp = (d * H_ + h) * W_ + ww;
      float po[NCLS];
#pragma unroll
      for (int c = 0; c < NCLS; ++c)
        po[c] = sigmoid_clip(x[(size_t)(b * CH + c * A_ + a) * SPAT + sp]);
      const float pg = pgt[(size_t)(b * A_ + a) * SPAT + sp];
      int cg = (int)pg - 1;  // astype(int32) truncation, then clip
      cg = min(max(cg, 0), NCLS - 1);
      const float pt = po[cg];
      const float wp = (1.0f - pt) * wcls[cg] * m;
      v[0] = -__logf(pt) * wp;
      v[1] = wp;
      const float ptgt = (pt > 0.5f) ? 1.0f : 0.0f;
#pragma unroll
      for (int c = 0; c < NCLS; ++c) {
        if (c == cg) continue;
        const float wo = fmaxf(po[c] - (pt - 0.1f), 0.0f) *
                         ((po[c] > 0.5f) ? 1.0f : 0.0f) * ptgt * m;
        v[2] += -__logf(1.0f - po[c]) * wo;
        v[3] += wo;
      }
    }
    {  // smooth-L1 regression
      const int* cd = cdiff + (b * K_ + k) * 4;
      const float md = (cd[0] > -1) ? 1.0f : 0.0f;
      const int a = max(cd[0], 0), d = max(cd[1], 0), h = max(cd[2], 0),
                ww = max(cd[3], 0);
      const int sp = (d * H_ + h) * W_ + ww;
#pragma unroll
      for (int j = 0; j < 6; ++j) {
        const float val = rp[(size_t)(b * 6 * A_ + j * A_ + a) * SPAT + sp];
        const float tgt = dgt[(b * K_ + k) * 6 + j];
        const float n = fabsf(val - tgt);
        const float s = (n < BETA_) ? (0.5f * n * n / BETA_) : (n - 0.5f * BETA_);
        v[4] += s * md;
      }
      v[5] = md;
    }
  }
  __shared__ float red[256][8];
#pragma unroll
  for (int j = 0; j < 8; ++j) red[tid][j] = v[j];
  __syncthreads();
  for (int s = 128; s > 0; s >>= 1) {
    if (tid < s) {
#pragma unroll
      for (int j = 0; j < 8; ++j) red[tid][j] += red[tid + s][j];
    }
    __syncthreads();
  }
  if (tid == 0) {
    const float l_pos = red[0][0], c_pos = red[0][1];
    const float l_oth = red[0][2], c_oth = red[0][3];
    const float l_reg = red[0][4], c_reg = red[0][5];
    const float l_neg = red[0][6], c_neg = red[0][7];
    out[0] = l_pos + l_neg + l_oth + l_reg;  // all lambdas = 1
    out[1] = l_pos;
    out[2] = l_neg;
    out[3] = l_oth;
    out[4] = l_reg;
    out[5] = c_pos;
    out[6] = c_neg;
    out[7] = c_oth;
    out[8] = c_reg;
  }
}

extern "C" void kernel_launch(void* const* d_in, const int* in_sizes, int n_in,
                              void* d_out, int out_size, void* d_ws,
                              size_t ws_size, hipStream_t stream) {
  const float* cls_logit = (const float*)d_in[0];
  const float* reg_pred = (const float*)d_in[1];
  const float* prob_gt = (const float*)d_in[2];
  const int* coord_prob = (const int*)d_in[3];
  const int* coord_diff = (const int*)d_in[4];
  const float* diff_gt = (const float*)d_in[5];
  const float* weight_cls = (const float*)d_in[6];
  float* out = (float*)d_out;
  float* ws = (float*)d_ws;  // [0..NBLK)=l_neg partials, [NBLK..2*NBLK)=count

  neg_loss_kernel<<<NBLK, 256, 0, stream>>>(cls_logit, prob_gt, ws);
  small_kernel<<<1, 256, 0, stream>>>(cls_logit, reg_pred, prob_gt, coord_prob,
                                      coord_diff, diff_gt, weight_cls, ws,
                                      out);
}

// Round 5
// 231.930 us; speedup vs baseline: 1.9213x; 1.0931x over previous
//
#include <hip/hip_runtime.h>
#include <cmath>

// Problem constants (from reference)
constexpr int B_ = 2, NCLS = 3, A_ = 3, D_ = 96, H_ = 96, W_ = 96, K_ = 128;
constexpr int CH = NCLS * A_;          // 9 channels in cls_logit
constexpr int HW = H_ * W_;            // 9216
constexpr int SPAT = D_ * HW;          // 884736
constexpr float EPS_ = 1e-4f;
constexpr float BETA_ = 1.0f / 9.0f;

// Wave-task decomposition: one wave (64 lanes = 4 h-rows x 16 w-segments,
// 6 w per lane) covers (b, c, h-group of 4, d-chunk of 6).
constexpr int WPL = 6;                 // w per lane
constexpr int DCHUNK = 6;
constexpr int NDC = D_ / DCHUNK;       // 16
constexpr int HGRP = 4;
constexpr int NHG = H_ / HGRP;         // 24
constexpr int NWAVES = B_ * CH * NHG * NDC;  // 6912
constexpr int NBLK = NWAVES / 4;             // 1728 blocks x 256 threads

static __device__ __forceinline__ float sigmoid_clip(float x) {
  float s = 1.0f / (1.0f + __expf(-x));
  return fminf(fmaxf(s, EPS_), 1.0f - EPS_);
}

static __device__ __forceinline__ void load6(const float* __restrict__ p,
                                             float* f) {
  const float2 u0 = *(const float2*)(p);
  const float2 u1 = *(const float2*)(p + 2);
  const float2 u2 = *(const float2*)(p + 4);
  f[0] = u0.x; f[1] = u0.y; f[2] = u1.x;
  f[3] = u1.y; f[4] = u2.x; f[5] = u2.y;
}

// ------- Kernel 1: negative focal loss, register sliding-window max ---------
// All global loads (x planes AND pg plane) are prefetched one d-iteration
// ahead; the loop body has no load->use dependency on a same-iteration load.
// Writes per-block partial sums to ws[blk] (l_neg) and ws[NBLK+blk] (count).
__global__ __launch_bounds__(256) void neg_loss_kernel(
    const float* __restrict__ x, const float* __restrict__ pgt,
    float* __restrict__ ws) {
  const int tid = threadIdx.x;
  const int lane = tid & 63;
  int t = blockIdx.x * 4 + (tid >> 6);   // wave-task id
  const int dci = t % NDC; t /= NDC;
  const int hg = t % NHG; t /= NHG;
  const int c = t % CH;
  const int b = t / CH;

  const int hl = lane >> 4;              // h within group: 0..3
  const int wseg = lane & 15;            // w segment: 0..15
  const int h = hg * HGRP + hl;
  const int w0 = wseg * WPL;
  const int d0 = dci * DCHUNK;
  const int a = c - (c / A_) * A_;       // c % 3

  const float* base = x + (size_t)(b * CH + c) * SPAT;
  const int hm = max(h - 1, 0), hq = min(h + 1, H_ - 1);
  const float* rowm = base + hm * W_ + w0;
  const float* rowc = base + h * W_ + w0;
  const float* rowp = base + hq * W_ + w0;
  const float* pgb = pgt + (size_t)(b * A_ + a) * SPAT + h * W_ + w0;

  float sprev[WPL], scur[WPL], ccur[WPL];
  float nm[6], nc[6], np[6];             // prefetched x plane d+1 (raw rows)
  float pgv[6];                          // prefetched pg plane d
  {
    float fm[6], fc[6], fp[6];
    const int plm = max(d0 - 1, 0) * HW;
    load6(rowm + plm, fm); load6(rowc + plm, fc); load6(rowp + plm, fp);
    const int pl0 = d0 * HW;
    float gm[6], gc[6], gp[6];
    load6(rowm + pl0, gm); load6(rowc + pl0, gc); load6(rowp + pl0, gp);
    // prefetch x plane d0+1 and pg plane d0
    const int pl1 = min(d0 + 1, D_ - 1) * HW;
    load6(rowm + pl1, nm); load6(rowc + pl1, nc); load6(rowp + pl1, np);
    load6(pgb + pl0, pgv);
#pragma unroll
    for (int i = 0; i < 6; ++i) sprev[i] = fmaxf(fmaxf(fm[i], fc[i]), fp[i]);
#pragma unroll
    for (int i = 0; i < 6; ++i) {
      scur[i] = fmaxf(fmaxf(gm[i], gc[i]), gp[i]);
      ccur[i] = gc[i];
    }
  }

  float lsum = 0.0f, csum = 0.0f;
#pragma unroll
  for (int k = 0; k < DCHUNK; ++k) {
    const int d = d0 + k;
    // consume prefetched x plane d+1 and pg plane d (issued last iteration)
    float snext[6], cnext[6], pgc[6];
#pragma unroll
    for (int i = 0; i < 6; ++i) {
      snext[i] = fmaxf(fmaxf(nm[i], nc[i]), np[i]);
      cnext[i] = nc[i];
      pgc[i] = pgv[i];
    }
    // issue prefetch for x plane d+2 and pg plane d+1
    const int pl2 = min(d + 2, D_ - 1) * HW;
    load6(rowm + pl2, nm); load6(rowc + pl2, nc); load6(rowp + pl2, np);
    load6(pgb + (d + 1 < D_ ? (d + 1) : d) * HW, pgv);

    float cmx[6], m[6];
#pragma unroll
    for (int i = 0; i < 6; ++i)
      cmx[i] = fmaxf(fmaxf(sprev[i], scur[i]), snext[i]);
    // cross-segment halo via wave shuffles (same h-row for wseg>0 / wseg<15)
    float left = __shfl_up(cmx[5], 1);
    float right = __shfl_down(cmx[0], 1);
    if (wseg == 0) left = cmx[0];      // w==0 clamps
    if (wseg == 15) right = cmx[5];    // w==95 clamps
    m[0] = fmaxf(left, fmaxf(cmx[0], cmx[1]));
    m[1] = fmaxf(cmx[0], fmaxf(cmx[1], cmx[2]));
    m[2] = fmaxf(cmx[1], fmaxf(cmx[2], cmx[3]));
    m[3] = fmaxf(cmx[2], fmaxf(cmx[3], cmx[4]));
    m[4] = fmaxf(cmx[3], fmaxf(cmx[4], cmx[5]));
    m[5] = fmaxf(cmx[4], fmaxf(cmx[5], right));

    // branchless accumulate: no memory dependency in the predicate path
#pragma unroll
    for (int i = 0; i < 6; ++i) {
      const float prob = sigmoid_clip(ccur[i]);
      const bool pred =
          (m[i] == ccur[i]) && (pgc[i] == -1.0f) && (prob > EPS_);
      lsum += pred ? (-__logf(1.0f - prob) * prob) : 0.0f;
      csum += pred ? prob : 0.0f;
    }
#pragma unroll
    for (int i = 0; i < 6; ++i) {
      sprev[i] = scur[i]; scur[i] = snext[i]; ccur[i] = cnext[i];
    }
  }

  // wave shuffle reduce then cross-wave via LDS; per-block partial to ws
#pragma unroll
  for (int off = 32; off > 0; off >>= 1) {
    lsum += __shfl_down(lsum, off);
    csum += __shfl_down(csum, off);
  }
  __shared__ float sl[4], sc[4];
  const int wv = tid >> 6;
  if (lane == 0) { sl[wv] = lsum; sc[wv] = csum; }
  __syncthreads();
  if (tid == 0) {
    ws[blockIdx.x] = sl[0] + sl[1] + sl[2] + sl[3];
    ws[NBLK + blockIdx.x] = sc[0] + sc[1] + sc[2] + sc[3];
  }
}

// ------ Kernel 2: K-point gathered terms + partial-sum reduce + output ------
__global__ __launch_bounds__(256) void small_kernel(
    const float* __restrict__ x, const float* __restrict__ rp,
    const float* __restrict__ pgt, const int* __restrict__ cprob,
    const int* __restrict__ cdiff, const float* __restrict__ dgt,
    const float* __restrict__ wcls, const float* __restrict__ ws,
    float* __restrict__ out) {
  const int tid = threadIdx.x;
  // v: l_pos, c_pos, l_oth, c_oth, l_reg, c_reg, l_neg, c_neg
  float v[8] = {0.f, 0.f, 0.f, 0.f, 0.f, 0.f, 0.f, 0.f};
  // reduce neg-loss per-block partials (coalesced strided)
  for (int i = tid; i < NBLK; i += 256) {
    v[6] += ws[i];
    v[7] += ws[NBLK + i];
  }
  if (tid < B_ * K_) {
    const int b = tid / K_, k = tid - b * K_;
    {  // positive focal + other-class suppression
      const int* cp = cprob + (b * K_ + k) * 4;
      const int ca = cp[0];
      const float m = (ca > -1) ? 1.0f : 0.0f;
      const int a = max(ca, 0), d = max(cp[1], 0), h = max(cp[2], 0),
                ww = max(cp[3], 0);
      const int sp = (d * H_ + h) * W_ + ww;
      float po[NCLS];
#pragma unroll
      for (int c = 0; c < NCLS; ++c)
        po[c] = sigmoid_clip(x[(size_t)(b * CH + c * A_ + a) * SPAT + sp]);
      const float pg = pgt[(size_t)(b * A_ + a) * SPAT + sp];
      int cg = (int)pg - 1;  // astype(int32) truncation, then clip
      cg = min(max(cg, 0), NCLS - 1);
      const float pt = po[cg];
      const float wp = (1.0f - pt) * wcls[cg] * m;
      v[0] = -__logf(pt) * wp;
      v[1] = wp;
      const float ptgt = (pt > 0.5f) ? 1.0f : 0.0f;
#pragma unroll
      for (int c = 0; c < NCLS; ++c) {
        if (c == cg) continue;
        const float wo = fmaxf(po[c] - (pt - 0.1f), 0.0f) *
                         ((po[c] > 0.5f) ? 1.0f : 0.0f) * ptgt * m;
        v[2] += -__logf(1.0f - po[c]) * wo;
        v[3] += wo;
      }
    }
    {  // smooth-L1 regression
      const int* cd = cdiff + (b * K_ + k) * 4;
      const float md = (cd[0] > -1) ? 1.0f : 0.0f;
      const int a = max(cd[0], 0), d = max(cd[1], 0), h = max(cd[2], 0),
                ww = max(cd[3], 0);
      const int sp = (d * H_ + h) * W_ + ww;
#pragma unroll
      for (int j = 0; j < 6; ++j) {
        const float val = rp[(size_t)(b * 6 * A_ + j * A_ + a) * SPAT + sp];
        const float tgt = dgt[(b * K_ + k) * 6 + j];
        const float n = fabsf(val - tgt);
        const float s = (n < BETA_) ? (0.5f * n * n / BETA_) : (n - 0.5f * BETA_);
        v[4] += s * md;
      }
      v[5] = md;
    }
  }
  __shared__ float red[256][8];
#pragma unroll
  for (int j = 0; j < 8; ++j) red[tid][j] = v[j];
  __syncthreads();
  for (int s = 128; s > 0; s >>= 1) {
    if (tid < s) {
#pragma unroll
      for (int j = 0; j < 8; ++j) red[tid][j] += red[tid + s][j];
    }
    __syncthreads();
  }
  if (tid == 0) {
    const float l_pos = red[0][0], c_pos = red[0][1];
    const float l_oth = red[0][2], c_oth = red[0][3];
    const float l_reg = red[0][4], c_reg = red[0][5];
    const float l_neg = red[0][6], c_neg = red[0][7];
    out[0] = l_pos + l_neg + l_oth + l_reg;  // all lambdas = 1
    out[1] = l_pos;
    out[2] = l_neg;
    out[3] = l_oth;
    out[4] = l_reg;
    out[5] = c_pos;
    out[6] = c_neg;
    out[7] = c_oth;
    out[8] = c_reg;
  }
}

extern "C" void kernel_launch(void* const* d_in, const int* in_sizes, int n_in,
                              void* d_out, int out_size, void* d_ws,
                              size_t ws_size, hipStream_t stream) {
  const float* cls_logit = (const float*)d_in[0];
  const float* reg_pred = (const float*)d_in[1];
  const float* prob_gt = (const float*)d_in[2];
  const int* coord_prob = (const int*)d_in[3];
  const int* coord_diff = (const int*)d_in[4];
  const float* diff_gt = (const float*)d_in[5];
  const float* weight_cls = (const float*)d_in[6];
  float* out = (float*)d_out;
  float* ws = (float*)d_ws;  // [0..NBLK)=l_neg partials, [NBLK..2*NBLK)=count

  neg_loss_kernel<<<NBLK, 256, 0, stream>>>(cls_logit, prob_gt, ws);
  small_kernel<<<1, 256, 0, stream>>>(cls_logit, reg_pred, prob_gt, coord_prob,
                                      coord_diff, diff_gt, weight_cls, ws,
                                      out);
}

// Round 6
// 231.923 us; speedup vs baseline: 1.9213x; 1.0000x over previous
//
#include <hip/hip_runtime.h>
#include <cmath>

// Problem constants (from reference)
constexpr int B_ = 2, NCLS = 3, A_ = 3, D_ = 96, H_ = 96, W_ = 96, K_ = 128;
constexpr int CH = NCLS * A_;          // 9 channels in cls_logit
constexpr int HW = H_ * W_;            // 9216
constexpr int SPAT = D_ * HW;          // 884736
constexpr float EPS_ = 1e-4f;
constexpr float BETA_ = 1.0f / 9.0f;

// Wave-task decomposition: one wave (64 lanes = 4 h-rows x 16 w-segments,
// 6 w per lane) covers (b, c, h-group of 4, d-chunk of 6).
constexpr int WPL = 6;                 // w per lane
constexpr int DCHUNK = 6;
constexpr int NDC = D_ / DCHUNK;       // 16
constexpr int HGRP = 4;
constexpr int NHG = H_ / HGRP;         // 24
constexpr int NWAVES = B_ * CH * NHG * NDC;  // 6912
constexpr int NBLK = NWAVES / 4;             // 1728 blocks x 256 threads

static __device__ __forceinline__ float sigmoid_clip(float x) {
  float s = 1.0f / (1.0f + __expf(-x));
  return fminf(fmaxf(s, EPS_), 1.0f - EPS_);
}

static __device__ __forceinline__ void load6(const float* __restrict__ p,
                                             float* f) {
  const float2 u0 = *(const float2*)(p);
  const float2 u1 = *(const float2*)(p + 2);
  const float2 u2 = *(const float2*)(p + 4);
  f[0] = u0.x; f[1] = u0.y; f[2] = u1.x;
  f[3] = u1.y; f[4] = u2.x; f[5] = u2.y;
}

// ------- Kernel 1: negative focal loss, register sliding-window max ---------
// Depth-2 software pipeline: raw rows of planes d+1 and d+2 (and pg planes
// d, d+1) live in parity-alternated register buffers, so every load is
// consumed two iterations after issue (~700 cyc slack > HBM latency).
// Writes per-block partial sums to ws[blk] (l_neg) and ws[NBLK+blk] (count).
__global__ __launch_bounds__(256) void neg_loss_kernel(
    const float* __restrict__ x, const float* __restrict__ pgt,
    float* __restrict__ ws) {
  const int tid = threadIdx.x;
  const int lane = tid & 63;
  int t = blockIdx.x * 4 + (tid >> 6);   // wave-task id
  const int dci = t % NDC; t /= NDC;
  const int hg = t % NHG; t /= NHG;
  const int c = t % CH;
  const int b = t / CH;

  const int hl = lane >> 4;              // h within group: 0..3
  const int wseg = lane & 15;            // w segment: 0..15
  const int h = hg * HGRP + hl;
  const int w0 = wseg * WPL;
  const int d0 = dci * DCHUNK;
  const int a = c - (c / A_) * A_;       // c % 3

  const float* base = x + (size_t)(b * CH + c) * SPAT;
  const int hm = max(h - 1, 0), hq = min(h + 1, H_ - 1);
  const float* rowm = base + hm * W_ + w0;
  const float* rowc = base + h * W_ + w0;
  const float* rowp = base + hq * W_ + w0;
  const float* pgb = pgt + (size_t)(b * A_ + a) * SPAT + h * W_ + w0;

  float sprev[6], scur[6], ccur[6];
  float bufm[2][6], bufc[2][6], bufp[2][6];  // raw x rows: planes d+1, d+2
  float pgbuf[2][6];                         // pg planes d, d+1
  {
    float fm[6], fc[6], fp[6], gm[6], gc[6], gp[6];
    const int plm = max(d0 - 1, 0) * HW;
    load6(rowm + plm, fm); load6(rowc + plm, fc); load6(rowp + plm, fp);
    const int pl0 = d0 * HW;
    load6(rowm + pl0, gm); load6(rowc + pl0, gc); load6(rowp + pl0, gp);
    const int pl1 = (d0 + 1) * HW;             // d0+1 <= 91, no clamp needed
    load6(rowm + pl1, bufm[0]); load6(rowc + pl1, bufc[0]);
    load6(rowp + pl1, bufp[0]);
    const int pl2 = (d0 + 2) * HW;             // d0+2 <= 92
    load6(rowm + pl2, bufm[1]); load6(rowc + pl2, bufc[1]);
    load6(rowp + pl2, bufp[1]);
    load6(pgb + pl0, pgbuf[0]);
    load6(pgb + pl1, pgbuf[1]);
#pragma unroll
    for (int i = 0; i < 6; ++i) sprev[i] = fmaxf(fmaxf(fm[i], fc[i]), fp[i]);
#pragma unroll
    for (int i = 0; i < 6; ++i) {
      scur[i] = fmaxf(fmaxf(gm[i], gc[i]), gp[i]);
      ccur[i] = gc[i];
    }
  }

  float lsum = 0.0f, csum = 0.0f;
#pragma unroll
  for (int k = 0; k < DCHUNK; ++k) {
    const int d = d0 + k;
    const int par = k & 1;
    // consume buffers filled two iterations ago (prologue for k=0,1)
    float snext[6], cnext[6], pgc[6];
#pragma unroll
    for (int i = 0; i < 6; ++i) {
      snext[i] = fmaxf(fmaxf(bufm[par][i], bufc[par][i]), bufp[par][i]);
      cnext[i] = bufc[par][i];
      pgc[i] = pgbuf[par][i];
    }
    // refill: x plane d+3 and pg plane d+2 (consumed at iteration k+2)
    const int pl3 = min(d + 3, D_ - 1) * HW;
    load6(rowm + pl3, bufm[par]); load6(rowc + pl3, bufc[par]);
    load6(rowp + pl3, bufp[par]);
    load6(pgb + min(d + 2, D_ - 1) * HW, pgbuf[par]);

    float cmx[6], m[6];
#pragma unroll
    for (int i = 0; i < 6; ++i)
      cmx[i] = fmaxf(fmaxf(sprev[i], scur[i]), snext[i]);
    // cross-segment halo via wave shuffles (same h-row for wseg>0 / wseg<15)
    float left = __shfl_up(cmx[5], 1);
    float right = __shfl_down(cmx[0], 1);
    if (wseg == 0) left = cmx[0];      // w==0 clamps
    if (wseg == 15) right = cmx[5];    // w==95 clamps
    m[0] = fmaxf(left, fmaxf(cmx[0], cmx[1]));
    m[1] = fmaxf(cmx[0], fmaxf(cmx[1], cmx[2]));
    m[2] = fmaxf(cmx[1], fmaxf(cmx[2], cmx[3]));
    m[3] = fmaxf(cmx[2], fmaxf(cmx[3], cmx[4]));
    m[4] = fmaxf(cmx[3], fmaxf(cmx[4], cmx[5]));
    m[5] = fmaxf(cmx[4], fmaxf(cmx[5], right));

    // branchless accumulate: no memory dependency in the predicate path
#pragma unroll
    for (int i = 0; i < 6; ++i) {
      const float prob = sigmoid_clip(ccur[i]);
      const bool pred =
          (m[i] == ccur[i]) && (pgc[i] == -1.0f) && (prob > EPS_);
      lsum += pred ? (-__logf(1.0f - prob) * prob) : 0.0f;
      csum += pred ? prob : 0.0f;
    }
#pragma unroll
    for (int i = 0; i < 6; ++i) {
      sprev[i] = scur[i]; scur[i] = snext[i]; ccur[i] = cnext[i];
    }
  }

  // wave shuffle reduce then cross-wave via LDS; per-block partial to ws
#pragma unroll
  for (int off = 32; off > 0; off >>= 1) {
    lsum += __shfl_down(lsum, off);
    csum += __shfl_down(csum, off);
  }
  __shared__ float sl[4], sc[4];
  const int wv = tid >> 6;
  if (lane == 0) { sl[wv] = lsum; sc[wv] = csum; }
  __syncthreads();
  if (tid == 0) {
    ws[blockIdx.x] = sl[0] + sl[1] + sl[2] + sl[3];
    ws[NBLK + blockIdx.x] = sc[0] + sc[1] + sc[2] + sc[3];
  }
}

// ------ Kernel 2: K-point gathered terms + partial-sum reduce + output ------
__global__ __launch_bounds__(256) void small_kernel(
    const float* __restrict__ x, const float* __restrict__ rp,
    const float* __restrict__ pgt, const int* __restrict__ cprob,
    const int* __restrict__ cdiff, const float* __restrict__ dgt,
    const float* __restrict__ wcls, const float* __restrict__ ws,
    float* __restrict__ out) {
  const int tid = threadIdx.x;
  // v: l_pos, c_pos, l_oth, c_oth, l_reg, c_reg, l_neg, c_neg
  float v[8] = {0.f, 0.f, 0.f, 0.f, 0.f, 0.f, 0.f, 0.f};
  // reduce neg-loss per-block partials (coalesced strided)
  for (int i = tid; i < NBLK; i += 256) {
    v[6] += ws[i];
    v[7] += ws[NBLK + i];
  }
  if (tid < B_ * K_) {
    const int b = tid / K_, k = tid - b * K_;
    {  // positive focal + other-class suppression
      const int* cp = cprob + (b * K_ + k) * 4;
      const int ca = cp[0];
      const float m = (ca > -1) ? 1.0f : 0.0f;
      const int a = max(ca, 0), d = max(cp[1], 0), h = max(cp[2], 0),
                ww = max(cp[3], 0);
      const int sp = (d * H_ + h) * W_ + ww;
      float po[NCLS];
#pragma unroll
      for (int c = 0; c < NCLS; ++c)
        po[c] = sigmoid_clip(x[(size_t)(b * CH + c * A_ + a) * SPAT + sp]);
      const float pg = pgt[(size_t)(b * A_ + a) * SPAT + sp];
      int cg = (int)pg - 1;  // astype(int32) truncation, then clip
      cg = min(max(cg, 0), NCLS - 1);
      const float pt = po[cg];
      const float wp = (1.0f - pt) * wcls[cg] * m;
      v[0] = -__logf(pt) * wp;
      v[1] = wp;
      const float ptgt = (pt > 0.5f) ? 1.0f : 0.0f;
#pragma unroll
      for (int c = 0; c < NCLS; ++c) {
        if (c == cg) continue;
        const float wo = fmaxf(po[c] - (pt - 0.1f), 0.0f) *
                         ((po[c] > 0.5f) ? 1.0f : 0.0f) * ptgt * m;
        v[2] += -__logf(1.0f - po[c]) * wo;
        v[3] += wo;
      }
    }
    {  // smooth-L1 regression
      const int* cd = cdiff + (b * K_ + k) * 4;
      const float md = (cd[0] > -1) ? 1.0f : 0.0f;
      const int a = max(cd[0], 0), d = max(cd[1], 0), h = max(cd[2], 0),
                ww = max(cd[3], 0);
      const int sp = (d * H_ + h) * W_ + ww;
#pragma unroll
      for (int j = 0; j < 6; ++j) {
        const float val = rp[(size_t)(b * 6 * A_ + j * A_ + a) * SPAT + sp];
        const float tgt = dgt[(b * K_ + k) * 6 + j];
        const float n = fabsf(val - tgt);
        const float s = (n < BETA_) ? (0.5f * n * n / BETA_) : (n - 0.5f * BETA_);
        v[4] += s * md;
      }
      v[5] = md;
    }
  }
  __shared__ float red[256][8];
#pragma unroll
  for (int j = 0; j < 8; ++j) red[tid][j] = v[j];
  __syncthreads();
  for (int s = 128; s > 0; s >>= 1) {
    if (tid < s) {
#pragma unroll
      for (int j = 0; j < 8; ++j) red[tid][j] += red[tid + s][j];
    }
    __syncthreads();
  }
  if (tid == 0) {
    const float l_pos = red[0][0], c_pos = red[0][1];
    const float l_oth = red[0][2], c_oth = red[0][3];
    const float l_reg = red[0][4], c_reg = red[0][5];
    const float l_neg = red[0][6], c_neg = red[0][7];
    out[0] = l_pos + l_neg + l_oth + l_reg;  // all lambdas = 1
    out[1] = l_pos;
    out[2] = l_neg;
    out[3] = l_oth;
    out[4] = l_reg;
    out[5] = c_pos;
    out[6] = c_neg;
    out[7] = c_oth;
    out[8] = c_reg;
  }
}

extern "C" void kernel_launch(void* const* d_in, const int* in_sizes, int n_in,
                              void* d_out, int out_size, void* d_ws,
                              size_t ws_size, hipStream_t stream) {
  const float* cls_logit = (const float*)d_in[0];
  const float* reg_pred = (const float*)d_in[1];
  const float* prob_gt = (const float*)d_in[2];
  const int* coord_prob = (const int*)d_in[3];
  const int* coord_diff = (const int*)d_in[4];
  const float* diff_gt = (const float*)d_in[5];
  const float* weight_cls = (const float*)d_in[6];
  float* out = (float*)d_out;
  float* ws = (float*)d_ws;  // [0..NBLK)=l_neg partials, [NBLK..2*NBLK)=count

  neg_loss_kernel<<<NBLK, 256, 0, stream>>>(cls_logit, prob_gt, ws);
  small_kernel<<<1, 256, 0, stream>>>(cls_logit, reg_pred, prob_gt, coord_prob,
                                      coord_diff, diff_gt, weight_cls, ws,
                                      out);
}